// Round 25
// baseline (477.748 us; speedup 1.0000x reference)
//
#include <hip/hip_runtime.h>
#include <hip/hip_bf16.h>

// GraphNet B=64,N=128,H=32,HE=64,OE=32,E_IN=66, 4 mp steps.
// Edge layer1 pre-act = P1[b,i,:] + P2[b,j,:] + dist*W1[64,:] + int*W1[65,:]
// dist via Gram: dist^2 = n_i + n_j - 2*dot.
// Round-25 (edge2 c-loop unroll 2; r24 = 452.5us validated): edge2 stuck at
// ~50us, VALUBusy 53%, wall ~2x VALU-busy time -> per-c dependent chain is
// the stall. Since r23 the 8 c-iterations are fully independent (own accg,
// own cbAll slot) -> unroll 2 gives the scheduler two parallel chains (ILP
// analog of the r22-r24 wave splits). VGPR 64 -> ~104-128 expected; occ cap
// 16 waves/CU > measured 10, shouldn't bind. Rest byte-identical to r24.

#define ALPHA 0.1f
#define BN_EPS 1e-5f
#define LRELU(v) ((v) > 0.f ? (v) : ALPHA * (v))

typedef __attribute__((ext_vector_type(8))) short short8v;
typedef __attribute__((ext_vector_type(4))) float f32x4;

union U8 { short8v v; unsigned int u[4]; };

__device__ __forceinline__ unsigned short bf16rne(float f) {
    unsigned int u = __float_as_uint(f);
    unsigned int r = u + 0x7fffu + ((u >> 16) & 1u);
    return (unsigned short)(r >> 16);
}
__device__ __forceinline__ float bf16tof(unsigned short h) {
    return __uint_as_float(((unsigned int)h) << 16);
}
__device__ __forceinline__ void cvt8(const float* y, unsigned int* hu, unsigned int* lu) {
#pragma unroll
    for (int p = 0; p < 4; ++p) {
        unsigned int hpair;
        asm("v_cvt_pk_bf16_f32 %0, %1, %2" : "=v"(hpair) : "v"(y[2*p]), "v"(y[2*p+1]));
        const float h0 = __uint_as_float(hpair << 16);
        const float h1 = __uint_as_float(hpair & 0xffff0000u);
        unsigned int lpair;
        const float r0 = y[2*p] - h0;
        const float r1 = y[2*p+1] - h1;
        asm("v_cvt_pk_bf16_f32 %0, %1, %2" : "=v"(lpair) : "v"(r0), "v"(r1));
        hu[p] = hpair;
        lu[p] = lpair;
    }
}

// ---------------- pad + step-0 prep: xc, P1, P2, nbuf ----------------
__global__ __launch_bounds__(128) void k_pad_prep(const float* __restrict__ x,
                                                  const float* __restrict__ W1,
                                                  const float* __restrict__ b1,
                                                  float* __restrict__ xc,
                                                  float* __restrict__ P1,
                                                  float* __restrict__ P2,
                                                  float2* __restrict__ nbuf) {
    __shared__ float w1s[384];
    __shared__ float b1s[64];
    const int tid = threadIdx.x;
    for (int u = tid; u < 384; u += 128) {
        const int r = u >> 6, c = u & 63;
        const int srow = (r < 3) ? r : (32 + r - 3);
        w1s[u] = W1[srow * 64 + c];
    }
    if (tid < 64) b1s[tid] = b1[tid];
    const int row = blockIdx.x * 128 + tid;
    const float x0 = x[row * 3 + 0], x1 = x[row * 3 + 1], x2 = x[row * 3 + 2];
    __syncthreads();
    float4* xp = (float4*)(xc + row * 32);
    xp[0] = make_float4(x0, x1, x2, 0.f);
    const float4 z4 = make_float4(0.f, 0.f, 0.f, 0.f);
#pragma unroll
    for (int u = 1; u < 8; ++u) xp[u] = z4;
    nbuf[row] = make_float2(x0 * x0 + x1 * x1 + x2 * x2, 0.f);
    float* p1p = P1 + row * 64;
    float* p2p = P2 + row * 64;
#pragma unroll
    for (int c = 0; c < 64; ++c) {
        p1p[c] = b1s[c] + x0 * w1s[c] + x1 * w1s[64 + c] + x2 * w1s[128 + c];
        p2p[c] = x0 * w1s[192 + c] + x1 * w1s[256 + c] + x2 * w1s[320 + c];
    }
}

// ---------------- edge pass 1: 512 threads, 16-col chunk per wave-pair ----
__global__ __launch_bounds__(512) void k_edge1(const float* __restrict__ xc,
                                               const float2* __restrict__ nbuf,
                                               const float* __restrict__ P1,
                                               const float* __restrict__ P2,
                                               const float* __restrict__ W1,
                                               float* __restrict__ stA) {
    __shared__ float xs[128 * 33];
    __shared__ float ddot[1024];
    __shared__ float2 nls[128];
    __shared__ float p1s[512];          // 8 il rows of P1
    __shared__ float red[256];          // 8 waves x 32 stats
    const int tid = threadIdx.x;
    const int b = blockIdx.x >> 4;
    const int ibase = (blockIdx.x & 15) * 8;
    const float* xg = xc + b * 4096;
    for (int u = tid; u < 4096; u += 512) xs[(u >> 5) * 33 + (u & 31)] = xg[u];
    if (tid < 128) nls[tid] = nbuf[b * 128 + tid];
    p1s[tid] = P1[(b * 128 + ibase + (tid >> 6)) * 64 + (tid & 63)];
    __syncthreads();
    {   // dot phase: 8 il rows x 128 j, 2 dots/thread
        const int il = tid >> 6, jb = tid & 63;
        const float* xi = &xs[(ibase + il) * 33];
        float xi_r[31];
#pragma unroll
        for (int k = 0; k < 31; ++k) xi_r[k] = xi[k];
        for (int q = 0; q < 2; ++q) {
            const int j = jb + 64 * q;
            const float* xj = &xs[j * 33];
            float d = 0.f;
#pragma unroll
            for (int k = 0; k < 31; ++k) d = fmaf(xi_r[k], xj[k], d);
            ddot[il * 128 + j] = d;
        }
    }
    __syncthreads();
    const int w = tid >> 6, l = tid & 63;
    const int tq = tid & 127;           // j row
    const int ch = (tid >> 7) * 16;     // this wave-pair's 16-col chunk
    const float2 nj = nls[tq];
    float4 p2v[4], wav[4], wbv[4];
    {
        const float* p2r = P2 + (b * 128 + tq) * 64 + ch;
        const float* war = W1 + 64 * 64 + ch;
        const float* wbr = W1 + 65 * 64 + ch;
#pragma unroll
        for (int u = 0; u < 4; ++u) {
            p2v[u] = *(const float4*)(p2r + u * 4);
            wav[u] = *(const float4*)(war + u * 4);
            wbv[u] = *(const float4*)(wbr + u * 4);
        }
    }
    float sum[16], sq[16];
#pragma unroll
    for (int k = 0; k < 16; ++k) { sum[k] = 0.f; sq[k] = 0.f; }
#pragma unroll 1
    for (int c = 0; c < 8; ++c) {
        const float2 ni = nls[ibase + c];
        const float dot = ddot[c * 128 + tq];
        const float dist = sqrtf(fmaxf(ni.x + nj.x - 2.f * dot, 0.f));
        const float itf = 1.f - (nj.y - ni.y);
        const float* p1r = &p1s[c * 64 + ch];
#pragma unroll
        for (int u = 0; u < 4; ++u) {
            const float4 p1v = *(const float4*)(p1r + u * 4);
            const float4 p2q = p2v[u];
            const float4 wa = wav[u];
            const float4 wb = wbv[u];
            float y0 = fmaf(itf, wb.x, fmaf(dist, wa.x, p1v.x + p2q.x));
            float y1 = fmaf(itf, wb.y, fmaf(dist, wa.y, p1v.y + p2q.y));
            float y2 = fmaf(itf, wb.z, fmaf(dist, wa.z, p1v.z + p2q.z));
            float y3 = fmaf(itf, wb.w, fmaf(dist, wa.w, p1v.w + p2q.w));
            y0 = LRELU(y0); y1 = LRELU(y1); y2 = LRELU(y2); y3 = LRELU(y3);
            sum[4*u+0] += y0; sq[4*u+0] += y0 * y0;
            sum[4*u+1] += y1; sq[4*u+1] += y1 * y1;
            sum[4*u+2] += y2; sq[4*u+2] += y2 * y2;
            sum[4*u+3] += y3; sq[4*u+3] += y3 * y3;
        }
    }
    // reduce-scatter over THIS WAVE's 32 stats (sum[0..15]|sq[0..15]).
    // Stage order (bit -> index weight): b5->16, b4->8, b3->4, b2->2, b1->1;
    // final mask-1 plain add completes the 64-lane reduction. Lane l ends
    // holding stat idx = l>>1 (duplicated even/odd).
    {
        const int b5 = (l >> 5) & 1;
#pragma unroll
        for (int i = 0; i < 16; ++i) {
            const float keep = b5 ? sq[i] : sum[i];
            const float send = b5 ? sum[i] : sq[i];
            sum[i] = keep + __shfl_xor(send, 32, 64);
        }
        const int b4 = (l >> 4) & 1;
#pragma unroll
        for (int i = 0; i < 8; ++i) {
            const float keep = b4 ? sum[i + 8] : sum[i];
            const float send = b4 ? sum[i] : sum[i + 8];
            sum[i] = keep + __shfl_xor(send, 16, 64);
        }
        const int b3 = (l >> 3) & 1;
#pragma unroll
        for (int i = 0; i < 4; ++i) {
            const float keep = b3 ? sum[i + 4] : sum[i];
            const float send = b3 ? sum[i] : sum[i + 4];
            sum[i] = keep + __shfl_xor(send, 8, 64);
        }
        const int b2 = (l >> 2) & 1;
#pragma unroll
        for (int i = 0; i < 2; ++i) {
            const float keep = b2 ? sum[i + 2] : sum[i];
            const float send = b2 ? sum[i] : sum[i + 2];
            sum[i] = keep + __shfl_xor(send, 4, 64);
        }
        const int b1 = (l >> 1) & 1;
        {
            const float keep = b1 ? sum[1] : sum[0];
            const float send = b1 ? sum[0] : sum[1];
            sum[0] = keep + __shfl_xor(send, 2, 64);
        }
        sum[0] += __shfl_xor(sum[0], 1, 64);   // final plain add over lane bit 0
    }
    if ((l & 1) == 0) red[w * 32 + (l >> 1)] = sum[0];
    __syncthreads();
    // combine per wave-PAIR: pair p (waves 2p,2p+1) covers cols [16p,16p+16)
    if (tid < 128) {
        const int p = tid >> 5;          // 0..3
        const int s = tid & 31;          // stat index
        const float val = red[p * 64 + s] + red[p * 64 + 32 + s];
        const int col = p * 16 + (s & 15);
        const int idx = (s < 16) ? col : (64 + col);   // stA: [0..63]=sum, [64..127]=sq
        atomicAdd(stA + idx, val);
    }
}

// ---------------- edge pass 2: 512 threads, 1 M-tile/wave ----------------
__global__ __launch_bounds__(512) void k_edge2(const float* __restrict__ xc,
                                               const float2* __restrict__ nbuf,
                                               const float* __restrict__ P1,
                                               const float* __restrict__ P2,
                                               const float* __restrict__ W1,
                                               const float* __restrict__ W2,
                                               const float* __restrict__ b2g,
                                               const float* __restrict__ g1,
                                               const float* __restrict__ bt1,
                                               const float* __restrict__ stA,
                                               float* __restrict__ stB,
                                               float* __restrict__ aggp) {
    __shared__ __align__(16) char smem_u[16896];     // xs (dot) / cbAll (16KB) after
    __shared__ float ddot[1024];
    __shared__ float2 nls[128];
    __shared__ unsigned short wfbs[4096];            // W2' frags: hi [0..2048), lo [2048..)
    __shared__ float s1s[64], t1s[64];
    __shared__ float p1s[512];                       // 8 il rows of P1
    __shared__ float part[256];
    __shared__ float b2ps[32];
    __shared__ float aggl[256];
    __shared__ float sqil[256];
    float* xs = (float*)smem_u;
    float* cbAll = (float*)smem_u;                   // [8 chunks][8 waves][64 slots]
    const int tid = threadIdx.x;
    const int b = blockIdx.x >> 4;
    const int ibase = (blockIdx.x & 15) * 8;
    const float* xg = xc + b * 4096;
    for (int u = tid; u < 4096; u += 512) xs[(u >> 5) * 33 + (u & 31)] = xg[u];
    if (tid < 128) nls[tid] = nbuf[b * 128 + tid];
    p1s[tid] = P1[(b * 128 + ibase + (tid >> 6)) * 64 + (tid & 63)];
    if (tid < 64) {
        const float ic = 1.f / 1048576.f;
        const float mu = stA[tid] * ic;
        const float var = stA[64 + tid] * ic - mu * mu;
        const float sv = g1[tid] * rsqrtf(var + BN_EPS);
        s1s[tid] = sv;
        t1s[tid] = bt1[tid] - mu * sv;
    }
    __syncthreads();
    {   // dot phase: 8 il rows x 128 j, 2 dots/thread
        const int il = tid >> 6, jb = tid & 63;
        const float* xi = &xs[(ibase + il) * 33];
        float xi_r[31];
#pragma unroll
        for (int k = 0; k < 31; ++k) xi_r[k] = xi[k];
        for (int q = 0; q < 2; ++q) {
            const int j = jb + 64 * q;
            const float* xj = &xs[j * 33];
            float d = 0.f;
#pragma unroll
            for (int k = 0; k < 31; ++k) d = fmaf(xi_r[k], xj[k], d);
            ddot[il * 128 + j] = d;
        }
    }
    if (tid < 256) {   // W2' hi/lo fragments into LDS (B-fragment order)
        const int ks2n = tid >> 6, L = tid & 63;
        const int ks = ks2n >> 1, n = ks2n & 1;
#pragma unroll
        for (int e = 0; e < 8; ++e) {
            const int k = (L >> 4) * 8 + e + 32 * ks;
            const int col = n * 16 + (L & 15);
            const float wv = W2[k * 32 + col] * s1s[k];
            const unsigned short hi = bf16rne(wv);
            const unsigned short lo = bf16rne(wv - bf16tof(hi));
            wfbs[(ks2n * 64 + L) * 8 + e] = hi;
            wfbs[2048 + (ks2n * 64 + L) * 8 + e] = lo;
        }
    }
    if (tid < 256) {   // b2' partials
        const int colp = tid & 31, kg2 = tid >> 5;
        float p = 0.f;
#pragma unroll
        for (int e = 0; e < 8; ++e) {
            const int k = kg2 * 8 + e;
            p = fmaf(t1s[k], W2[k * 32 + colp], p);
        }
        part[kg2 * 32 + colp] = p;
    }
    __syncthreads();
    if (tid < 32) {
        float acc = b2g[tid];
#pragma unroll
        for (int g = 0; g < 8; ++g) acc += part[g * 32 + tid];
        b2ps[tid] = acc;
    }
    const int w = tid >> 6, l = tid & 63;
    short8v bfh[2][2], bfl[2][2];
#pragma unroll
    for (int ks = 0; ks < 2; ++ks)
#pragma unroll
        for (int n = 0; n < 2; ++n) {
            bfh[ks][n] = *(const short8v*)(wfbs + ((ks * 2 + n) * 64 + l) * 8);
            bfl[ks][n] = *(const short8v*)(wfbs + 2048 + ((ks * 2 + n) * 64 + l) * 8);
        }
    __syncthreads();                     // b2ps ready; xs dead -> cbAll reuse
    const float b2p0 = b2ps[l & 15];
    const float b2p1 = b2ps[16 + (l & 15)];
    const int kb = (l >> 4) * 8;         // this lane's k-slice base
    const int lb4 = (l >> 4) & 1;        // epilogue scatter bits
    const int lb5 = (l >> 5) & 1;
    const float* wab = W1 + 64 * 64;
    const float* wbb = W1 + 65 * 64;
    const float4 waA0 = *(const float4*)(wab + kb);
    const float4 waA1 = *(const float4*)(wab + kb + 4);
    const float4 waB0 = *(const float4*)(wab + 32 + kb);
    const float4 waB1 = *(const float4*)(wab + 32 + kb + 4);
    const float4 wbA0 = *(const float4*)(wbb + kb);
    const float4 wbA1 = *(const float4*)(wbb + kb + 4);
    const float4 wbB0 = *(const float4*)(wbb + 32 + kb);
    const float4 wbB1 = *(const float4*)(wbb + 32 + kb + 4);
    const int jrow = w * 16 + (l & 15);  // ONE M-tile per wave
    const float2 nj = nls[jrow];
    float4 p2rv[4];
    {
        const float* p2b = P2 + (b * 128 + jrow) * 64;
        p2rv[0] = *(const float4*)(p2b + kb);
        p2rv[1] = *(const float4*)(p2b + kb + 4);
        p2rv[2] = *(const float4*)(p2b + 32 + kb);
        p2rv[3] = *(const float4*)(p2b + 32 + kb + 4);
    }

#pragma unroll 2
    for (int c = 0; c < 8; ++c) {
        const float2 ni = nls[ibase + c];
        const float* p1b = &p1s[c * 64];
        const float4 p1A0 = *(const float4*)(p1b + kb);
        const float4 p1A1 = *(const float4*)(p1b + kb + 4);
        const float4 p1B0 = *(const float4*)(p1b + 32 + kb);
        const float4 p1B1 = *(const float4*)(p1b + 32 + kb + 4);
        const float dot = ddot[c * 128 + jrow];
        const float dist = sqrtf(fmaxf(ni.x + nj.x - 2.f * dot, 0.f));
        const float itf = 1.f - (nj.y - ni.y);
        const float4 p20 = p2rv[0];
        const float4 p21 = p2rv[1];
        const float4 p22 = p2rv[2];
        const float4 p23 = p2rv[3];
        float ya[8], yb[8];
        ya[0] = LRELU(fmaf(itf, wbA0.x, fmaf(dist, waA0.x, p1A0.x + p20.x)));
        ya[1] = LRELU(fmaf(itf, wbA0.y, fmaf(dist, waA0.y, p1A0.y + p20.y)));
        ya[2] = LRELU(fmaf(itf, wbA0.z, fmaf(dist, waA0.z, p1A0.z + p20.z)));
        ya[3] = LRELU(fmaf(itf, wbA0.w, fmaf(dist, waA0.w, p1A0.w + p20.w)));
        ya[4] = LRELU(fmaf(itf, wbA1.x, fmaf(dist, waA1.x, p1A1.x + p21.x)));
        ya[5] = LRELU(fmaf(itf, wbA1.y, fmaf(dist, waA1.y, p1A1.y + p21.y)));
        ya[6] = LRELU(fmaf(itf, wbA1.z, fmaf(dist, waA1.z, p1A1.z + p21.z)));
        ya[7] = LRELU(fmaf(itf, wbA1.w, fmaf(dist, waA1.w, p1A1.w + p21.w)));
        yb[0] = LRELU(fmaf(itf, wbB0.x, fmaf(dist, waB0.x, p1B0.x + p22.x)));
        yb[1] = LRELU(fmaf(itf, wbB0.y, fmaf(dist, waB0.y, p1B0.y + p22.y)));
        yb[2] = LRELU(fmaf(itf, wbB0.z, fmaf(dist, waB0.z, p1B0.z + p22.z)));
        yb[3] = LRELU(fmaf(itf, wbB0.w, fmaf(dist, waB0.w, p1B0.w + p22.w)));
        yb[4] = LRELU(fmaf(itf, wbB1.x, fmaf(dist, waB1.x, p1B1.x + p23.x)));
        yb[5] = LRELU(fmaf(itf, wbB1.y, fmaf(dist, waB1.y, p1B1.y + p23.y)));
        yb[6] = LRELU(fmaf(itf, wbB1.z, fmaf(dist, waB1.z, p1B1.z + p23.z)));
        yb[7] = LRELU(fmaf(itf, wbB1.w, fmaf(dist, waB1.w, p1B1.w + p23.w)));
        U8 a0h, a0l, a1h, a1l;
        cvt8(ya, a0h.u, a0l.u);
        cvt8(yb, a1h.u, a1l.u);
        f32x4 acc0 = {0.f, 0.f, 0.f, 0.f};
        f32x4 acc1 = {0.f, 0.f, 0.f, 0.f};
        acc0 = __builtin_amdgcn_mfma_f32_16x16x32_bf16(a0h.v, bfh[0][0], acc0, 0, 0, 0);
        acc0 = __builtin_amdgcn_mfma_f32_16x16x32_bf16(a0h.v, bfl[0][0], acc0, 0, 0, 0);
        acc0 = __builtin_amdgcn_mfma_f32_16x16x32_bf16(a0l.v, bfh[0][0], acc0, 0, 0, 0);
        acc0 = __builtin_amdgcn_mfma_f32_16x16x32_bf16(a1h.v, bfh[1][0], acc0, 0, 0, 0);
        acc0 = __builtin_amdgcn_mfma_f32_16x16x32_bf16(a1h.v, bfl[1][0], acc0, 0, 0, 0);
        acc0 = __builtin_amdgcn_mfma_f32_16x16x32_bf16(a1l.v, bfh[1][0], acc0, 0, 0, 0);
        acc1 = __builtin_amdgcn_mfma_f32_16x16x32_bf16(a0h.v, bfh[0][1], acc1, 0, 0, 0);
        acc1 = __builtin_amdgcn_mfma_f32_16x16x32_bf16(a0h.v, bfl[0][1], acc1, 0, 0, 0);
        acc1 = __builtin_amdgcn_mfma_f32_16x16x32_bf16(a0l.v, bfh[0][1], acc1, 0, 0, 0);
        acc1 = __builtin_amdgcn_mfma_f32_16x16x32_bf16(a1h.v, bfh[1][1], acc1, 0, 0, 0);
        acc1 = __builtin_amdgcn_mfma_f32_16x16x32_bf16(a1h.v, bfl[1][1], acc1, 0, 0, 0);
        acc1 = __builtin_amdgcn_mfma_f32_16x16x32_bf16(a1l.v, bfh[1][1], acc1, 0, 0, 0);
        float s0 = 0.f, q0 = 0.f, s1 = 0.f, q1 = 0.f;
#pragma unroll
        for (int r4 = 0; r4 < 4; ++r4) {
            const float z0 = LRELU(acc0[r4] + b2p0);
            const float z1 = LRELU(acc1[r4] + b2p1);
            s0 += z0; q0 += z0 * z0;
            s1 += z1; q1 += z1 * z1;
        }
        // reduce-scatter over lane bits 4,5: lane group keeps one of {s0,s1,q0,q1}
        float sA = lb4 ? s1 : s0;
        float sB = lb4 ? s0 : s1;
        float qA = lb4 ? q1 : q0;
        float qB = lb4 ? q0 : q1;
        sA += __shfl_xor(sB, 16, 64);
        qA += __shfl_xor(qB, 16, 64);
        float vA = lb5 ? qA : sA;
        float vB = lb5 ? sA : qA;
        vA += __shfl_xor(vB, 32, 64);
        // slot: [s c0-15 | s c16-31 | q c0-15 | q c16-31] per wave
        cbAll[c * 512 + w * 64 + lb5 * 32 + lb4 * 16 + (l & 15)] = vA;
    }
    __syncthreads();
    if (tid < 256) {
        const int c2 = tid >> 5, col = tid & 31;
        const float* base = cbAll + c2 * 512;
        float s = 0.f, qq = 0.f;
#pragma unroll
        for (int wv = 0; wv < 8; ++wv) {
            s  += base[wv * 64 + col];
            qq += base[wv * 64 + 32 + col];
        }
        aggp[(b * 128 + ibase + c2) * 32 + col] = s;
        aggl[c2 * 32 + col] = s;
        sqil[c2 * 32 + col] = qq;
    }
    __syncthreads();
    if (tid < 32) {
        float s = 0.f, qq = 0.f;
#pragma unroll
        for (int il3 = 0; il3 < 8; ++il3) { s += aggl[il3 * 32 + tid]; qq += sqil[il3 * 32 + tid]; }
        atomicAdd(stB + tid, s);
        atomicAdd(stB + 32 + tid, qq);
    }
}

// ---------------- software grid barrier (all blocks co-resident) ----------------
__device__ __forceinline__ void gbar(unsigned int* ctr, unsigned int target) {
    __syncthreads();
    if (threadIdx.x == 0) {
        __hip_atomic_fetch_add(ctr, 1u, __ATOMIC_ACQ_REL, __HIP_MEMORY_SCOPE_AGENT);
        while (__hip_atomic_load(ctr, __ATOMIC_ACQUIRE, __HIP_MEMORY_SCOPE_AGENT) < target) {
            __builtin_amdgcn_s_sleep(2);
        }
    }
    __syncthreads();
}

// ---------------- fused node MLP: 4 threads/row, 128 blocks x 256 threads ----
// row = blockIdx*64 + (tid>>2); part = tid&3 owns output cols [8p, 8p+8).
__global__ __launch_bounds__(256) void k_nodeF(
    const float* __restrict__ aggp, const float* __restrict__ xc,
    const float* __restrict__ W0, const float* __restrict__ b0,
    const float* __restrict__ stB, const float* __restrict__ g2, const float* __restrict__ bt2,
    const float* __restrict__ W1m, const float* __restrict__ b1m,
    float* __restrict__ stC, const float* __restrict__ gC, const float* __restrict__ btC,
    const float* __restrict__ W2m, const float* __restrict__ b2m,
    float* __restrict__ stD, const float* __restrict__ gD, const float* __restrict__ btD,
    float* __restrict__ xout,
    const float* __restrict__ W1n, const float* __restrict__ b1n,
    float* __restrict__ P1, float* __restrict__ P2, float2* __restrict__ nbuf,
    unsigned int* __restrict__ bar, int doPrep)
{
    __shared__ float w0s[2048];
    __shared__ float wms[1024];
    __shared__ float wus[1024];
    __shared__ float w1s[4096];
    __shared__ float b0s[32], s2s[32], t2s[32];
    __shared__ float bms[32], sCs[32], tCs[32];
    __shared__ float bus[32], sDs[32], tDs[32];
    __shared__ float b1s[64];
    __shared__ float red[256];
    const int tid = threadIdx.x;
    const int l = tid & 63, w = tid >> 6;
    const int part = tid & 3;
    const int row = blockIdx.x * 64 + (tid >> 2);
    const int ob = part * 8;            // this thread's output col base (8 cols)
    const int gbase = l & ~3;           // base lane of this row's 4-lane group
    for (int k = tid; k < 2048; k += 256) w0s[k] = W0[k];
    for (int k = tid; k < 1024; k += 256) { wms[k] = W1m[k]; wus[k] = W2m[k]; }
    if (doPrep) {
        for (int k = tid; k < 4096; k += 256) w1s[k] = W1n[k];
        if (tid < 64) b1s[tid] = b1n[tid];
    }
    if (tid < 32) {
        b0s[tid] = b0[tid]; bms[tid] = b1m[tid]; bus[tid] = b2m[tid];
        const float ic = 1.f / 1048576.f;
        const float mu = stB[tid] * ic;
        const float var = stB[32 + tid] * ic - mu * mu;
        const float sv = g2[tid] * rsqrtf(var + BN_EPS);
        s2s[tid] = sv; t2s[tid] = bt2[tid] - mu * sv;
    }
    __syncthreads();
    // ---- load full row input h[64] (4x duplicated across the row's lanes) ----
    float h[64];
    {
        const float4* ap = (const float4*)(aggp + row * 32);
        const float4* xp = (const float4*)(xc + row * 32);
#pragma unroll
        for (int u = 0; u < 8; ++u) {
            const float4 a = ap[u];
            h[4*u+0] = fmaf(s2s[4*u+0], a.x, 128.f * t2s[4*u+0]);
            h[4*u+1] = fmaf(s2s[4*u+1], a.y, 128.f * t2s[4*u+1]);
            h[4*u+2] = fmaf(s2s[4*u+2], a.z, 128.f * t2s[4*u+2]);
            h[4*u+3] = fmaf(s2s[4*u+3], a.w, 128.f * t2s[4*u+3]);
            const float4 xv = xp[u];
            h[32+4*u+0] = xv.x; h[32+4*u+1] = xv.y; h[32+4*u+2] = xv.z; h[32+4*u+3] = xv.w;
        }
    }
    // ---- GEMM1: 8 outputs ----
    float v[8];
#pragma unroll
    for (int oo = 0; oo < 8; oo += 4) {
        const int o0 = ob + oo;
        float z0 = b0s[o0], z1 = b0s[o0+1], z2 = b0s[o0+2], z3 = b0s[o0+3];
#pragma unroll
        for (int k = 0; k < 64; ++k) {
            const float4 wv = *(const float4*)&w0s[k * 32 + o0];
            const float hv = h[k];
            z0 = fmaf(hv, wv.x, z0); z1 = fmaf(hv, wv.y, z1);
            z2 = fmaf(hv, wv.z, z2); z3 = fmaf(hv, wv.w, z3);
        }
        v[oo] = LRELU(z0); v[oo+1] = LRELU(z1); v[oo+2] = LRELU(z2); v[oo+3] = LRELU(z3);
    }
    // ---- stats of v -> stC (butterfly over 16 rows of the wave) ----
    {
        float st[16];
#pragma unroll
        for (int i = 0; i < 8; ++i) { st[i] = v[i]; st[8 + i] = v[i] * v[i]; }
#pragma unroll
        for (int m = 4; m <= 32; m <<= 1) {
#pragma unroll
            for (int i = 0; i < 16; ++i) st[i] += __shfl_xor(st[i], m, 64);
        }
        if (l < 4) {
#pragma unroll
            for (int i = 0; i < 16; ++i) red[w * 64 + (l & 3) * 16 + i] = st[i];
        }
    }
    __syncthreads();
    if (tid < 64) {
        const float val = red[tid] + red[64 + tid] + red[128 + tid] + red[192 + tid];
        const int p2i = tid >> 4;
        const int ii = tid & 15;
        const int col = p2i * 8 + (ii & 7);
        const int isq = (ii >> 3) & 1;
        atomicAdd(stC + isq * 32 + col, val);
    }
    gbar(bar + 0, 128);
    if (tid < 32) {
        const float ic = 1.f / 8192.f;
        const float mu = __hip_atomic_load(stC + tid, __ATOMIC_RELAXED, __HIP_MEMORY_SCOPE_AGENT) * ic;
        const float sq = __hip_atomic_load(stC + 32 + tid, __ATOMIC_RELAXED, __HIP_MEMORY_SCOPE_AGENT) * ic;
        const float var = sq - mu * mu;
        const float sv = gC[tid] * rsqrtf(var + BN_EPS);
        sCs[tid] = sv; tCs[tid] = btC[tid] - mu * sv;
    }
    __syncthreads();
    // ---- all-gather v -> vf[32]; hh = BN ----
    float hh[32];
    {
#pragma unroll
        for (int g = 0; g < 4; ++g) {
#pragma unroll
            for (int i = 0; i < 8; ++i) {
                const float val = __shfl(v[i], gbase + g, 64);
                hh[g * 8 + i] = fmaf(sCs[g * 8 + i], val, tCs[g * 8 + i]);
            }
        }
    }
    // ---- GEMM2: 8 outputs ----
    float v2[8];
#pragma unroll
    for (int oo = 0; oo < 8; oo += 4) {
        const int o0 = ob + oo;
        float z0 = bms[o0], z1 = bms[o0+1], z2 = bms[o0+2], z3 = bms[o0+3];
#pragma unroll
        for (int k = 0; k < 32; ++k) {
            const float4 wv = *(const float4*)&wms[k * 32 + o0];
            const float hv = hh[k];
            z0 = fmaf(hv, wv.x, z0); z1 = fmaf(hv, wv.y, z1);
            z2 = fmaf(hv, wv.z, z2); z3 = fmaf(hv, wv.w, z3);
        }
        v2[oo] = LRELU(z0); v2[oo+1] = LRELU(z1); v2[oo+2] = LRELU(z2); v2[oo+3] = LRELU(z3);
    }
    // ---- stats of v2 -> stD ----
    {
        float st[16];
#pragma unroll
        for (int i = 0; i < 8; ++i) { st[i] = v2[i]; st[8 + i] = v2[i] * v2[i]; }
#pragma unroll
        for (int m = 4; m <= 32; m <<= 1) {
#pragma unroll
            for (int i = 0; i < 16; ++i) st[i] += __shfl_xor(st[i], m, 64);
        }
        __syncthreads();                 // red reuse
        if (l < 4) {
#pragma unroll
            for (int i = 0; i < 16; ++i) red[w * 64 + (l & 3) * 16 + i] = st[i];
        }
    }
    __syncthreads();
    if (tid < 64) {
        const float val = red[tid] + red[64 + tid] + red[128 + tid] + red[192 + tid];
        const int p2i = tid >> 4;
        const int ii = tid & 15;
        const int col = p2i * 8 + (ii & 7);
        const int isq = (ii >> 3) & 1;
        atomicAdd(stD + isq * 32 + col, val);
    }
    gbar(bar + 1, 128);
    if (tid < 32) {
        const float ic = 1.f / 8192.f;
        const float mu = __hip_atomic_load(stD + tid, __ATOMIC_RELAXED, __HIP_MEMORY_SCOPE_AGENT) * ic;
        const float sq = __hip_atomic_load(stD + 32 + tid, __ATOMIC_RELAXED, __HIP_MEMORY_SCOPE_AGENT) * ic;
        const float var = sq - mu * mu;
        const float sv = gD[tid] * rsqrtf(var + BN_EPS);
        sDs[tid] = sv; tDs[tid] = btD[tid] - mu * sv;
    }
    __syncthreads();
    // ---- all-gather v2 -> h3 = BN(v2) ----
    float h3[32];
    {
#pragma unroll
        for (int g = 0; g < 4; ++g) {
#pragma unroll
            for (int i = 0; i < 8; ++i) {
                const float val = __shfl(v2[i], gbase + g, 64);
                h3[g * 8 + i] = fmaf(sDs[g * 8 + i], val, tDs[g * 8 + i]);
            }
        }
    }
    // ---- GEMM3 (Wu) + tanh: 8 outputs ----
    float xn[8];
#pragma unroll
    for (int oo = 0; oo < 8; oo += 4) {
        const int o0 = ob + oo;
        float z0 = bus[o0], z1 = bus[o0+1], z2 = bus[o0+2], z3 = bus[o0+3];
#pragma unroll
        for (int k = 0; k < 32; ++k) {
            const float4 wv = *(const float4*)&wus[k * 32 + o0];
            const float hv = h3[k];
            z0 = fmaf(hv, wv.x, z0); z1 = fmaf(hv, wv.y, z1);
            z2 = fmaf(hv, wv.z, z2); z3 = fmaf(hv, wv.w, z3);
        }
        xn[oo]   = tanhf(z0);
        xn[oo+1] = tanhf(z1);
        xn[oo+2] = tanhf(z2);
        xn[oo+3] = tanhf(z3);
    }
    {
        float* xp = xout + row * 32 + ob;
        *(float4*)(xp)     = make_float4(xn[0], xn[1], xn[2], xn[3]);
        *(float4*)(xp + 4) = make_float4(xn[4], xn[5], xn[6], xn[7]);
    }
    if (!doPrep) return;
    // ---- all-gather xn -> xnf[32]; prep P1/P2 cols [16p, 16p+16) ----
    float xnf[32];
    {
#pragma unroll
        for (int g = 0; g < 4; ++g) {
#pragma unroll
            for (int i = 0; i < 8; ++i) {
                xnf[g * 8 + i] = __shfl(xn[i], gbase + g, 64);
            }
        }
    }
    if (part == 0) {
        float n = 0.f;
#pragma unroll
        for (int k = 0; k < 31; ++k) n = fmaf(xnf[k], xnf[k], n);
        nbuf[row] = make_float2(n, xnf[31]);
    }
    const int cb = part * 16;
    float* p1p = P1 + row * 64 + cb;
    float* p2p = P2 + row * 64 + cb;
#pragma unroll
    for (int c0 = 0; c0 < 16; c0 += 4) {
        const int col = cb + c0;
        float a0 = b1s[col], a1 = b1s[col+1], a2 = b1s[col+2], a3 = b1s[col+3];
        float q0 = 0.f, q1 = 0.f, q2 = 0.f, q3 = 0.f;
#pragma unroll
        for (int k = 0; k < 32; ++k) {
            const float xv = xnf[k];
            const float4 wa = *(const float4*)&w1s[k * 64 + col];
            const float4 wb = *(const float4*)&w1s[(32 + k) * 64 + col];
            a0 = fmaf(xv, wa.x, a0); a1 = fmaf(xv, wa.y, a1);
            a2 = fmaf(xv, wa.z, a2); a3 = fmaf(xv, wa.w, a3);
            q0 = fmaf(xv, wb.x, q0); q1 = fmaf(xv, wb.y, q1);
            q2 = fmaf(xv, wb.z, q2); q3 = fmaf(xv, wb.w, q3);
        }
        *(float4*)(p1p + c0) = make_float4(a0, a1, a2, a3);
        *(float4*)(p2p + c0) = make_float4(q0, q1, q2, q3);
    }
}

extern "C" void kernel_launch(void* const* d_in, const int* in_sizes, int n_in,
                              void* d_out, int out_size, void* d_ws, size_t ws_size,
                              hipStream_t stream) {
    const float* x    = (const float*)d_in[0];
    const float* Wah  = (const float*)d_in[1];
    const float* bah  = (const float*)d_in[2];
    const float* Wa   = (const float*)d_in[3];
    const float* ba   = (const float*)d_in[4];
    const float* g_eh = (const float*)d_in[5];
    const float* b_eh = (const float*)d_in[6];
    const float* g_e  = (const float*)d_in[7];
    const float* b_e  = (const float*)d_in[8];
    const float* Wn0  = (const float*)d_in[9];
    const float* bn0  = (const float*)d_in[10];
    const float* Wn   = (const float*)d_in[11];
    const float* bnn  = (const float*)d_in[12];
    const float* g_n  = (const float*)d_in[13];
    const float* b_n  = (const float*)d_in[14];
    const float* Wu   = (const float*)d_in[15];
    const float* bu   = (const float*)d_in[16];

    float* ws    = (float*)d_ws;
    float* xc    = ws;                 // 262144
    float* aggp  = ws + 262144;        // 262144
    float* P1    = ws + 786432;        // 524288
    float* P2    = ws + 1310720;       // 524288
    float2* nbuf = (float2*)(ws + 1835008);  // 16384 float2
    float* stats = ws + 1867776;       // 1280 (320/step)
    unsigned int* bar = (unsigned int*)(ws + 1869056);  // 16 counters
    float* out   = (float*)d_out;

    hipMemsetAsync(stats, 0, (1280 + 16) * sizeof(float), stream);
    k_pad_prep<<<64, 128, 0, stream>>>(x, Wah, bah, xc, P1, P2, nbuf);

    for (int s = 0; s < 4; ++s) {
        const float* W1 = Wah + s * 66 * 64;
        const float* W2 = Wa + s * 64 * 32;
        const float* b2 = ba + s * 32;
        float* stA = stats + s * 320;
        float* stB = stA + 128;
        float* stC = stA + 192;
        float* stD = stA + 256;

        k_edge1<<<1024, 512, 0, stream>>>(xc, nbuf, P1, P2, W1, stA);
        k_edge2<<<1024, 512, 0, stream>>>(xc, nbuf, P1, P2, W1, W2, b2,
                                          g_eh + s * 64, b_eh + s * 64, stA, stB, aggp);
        k_nodeF<<<128, 256, 0, stream>>>(aggp, xc, Wn0 + s * 2048, bn0 + s * 32,
                                        stB, g_e + s * 32, b_e + s * 32,
                                        Wn + s * 1024, bnn + s * 32,
                                        stC, g_n + s * 64, b_n + s * 64,
                                        Wu + s * 1024, bu + s * 32,
                                        stD, g_n + s * 64 + 32, b_n + s * 64 + 32,
                                        (s == 3) ? out : xc,
                                        (s < 3) ? (Wah + (s + 1) * 66 * 64) : Wah,
                                        (s < 3) ? (bah + (s + 1) * 64) : bah,
                                        P1, P2, nbuf, bar + s * 2, (s < 3) ? 1 : 0);
    }
}

// Round 26
// 440.428 us; speedup vs baseline: 1.0847x; 1.0847x over previous
//
#include <hip/hip_runtime.h>
#include <hip/hip_bf16.h>

// GraphNet B=64,N=128,H=32,HE=64,OE=32,E_IN=66, 4 mp steps.
// Edge layer1 pre-act = P1[b,i,:] + P2[b,j,:] + dist*W1[64,:] + int*W1[65,:]
// dist via Gram: dist^2 = n_i + n_j - 2*dot.
// Round-26: r25's unroll-2 regressed (occ 31->19.5%, 50->60us) -> reverted to
// unroll 1. Single new variable: dist-hoist — the dot phase now stores
// dist = sqrt(max(ni+nj-2*dot,0)) directly into ddot (it has nls in LDS),
// removing sqrt+fmax+fma from the per-c serial chain of BOTH edge main loops
// and cutting sqrt count 4x. Bitwise-identical formula/order. Rest = r24
// (452.5us validated): 512-thread edge kernels, sharded nodeF, grid barrier.

#define ALPHA 0.1f
#define BN_EPS 1e-5f
#define LRELU(v) ((v) > 0.f ? (v) : ALPHA * (v))

typedef __attribute__((ext_vector_type(8))) short short8v;
typedef __attribute__((ext_vector_type(4))) float f32x4;

union U8 { short8v v; unsigned int u[4]; };

__device__ __forceinline__ unsigned short bf16rne(float f) {
    unsigned int u = __float_as_uint(f);
    unsigned int r = u + 0x7fffu + ((u >> 16) & 1u);
    return (unsigned short)(r >> 16);
}
__device__ __forceinline__ float bf16tof(unsigned short h) {
    return __uint_as_float(((unsigned int)h) << 16);
}
__device__ __forceinline__ void cvt8(const float* y, unsigned int* hu, unsigned int* lu) {
#pragma unroll
    for (int p = 0; p < 4; ++p) {
        unsigned int hpair;
        asm("v_cvt_pk_bf16_f32 %0, %1, %2" : "=v"(hpair) : "v"(y[2*p]), "v"(y[2*p+1]));
        const float h0 = __uint_as_float(hpair << 16);
        const float h1 = __uint_as_float(hpair & 0xffff0000u);
        unsigned int lpair;
        const float r0 = y[2*p] - h0;
        const float r1 = y[2*p+1] - h1;
        asm("v_cvt_pk_bf16_f32 %0, %1, %2" : "=v"(lpair) : "v"(r0), "v"(r1));
        hu[p] = hpair;
        lu[p] = lpair;
    }
}

// ---------------- pad + step-0 prep: xc, P1, P2, nbuf ----------------
__global__ __launch_bounds__(128) void k_pad_prep(const float* __restrict__ x,
                                                  const float* __restrict__ W1,
                                                  const float* __restrict__ b1,
                                                  float* __restrict__ xc,
                                                  float* __restrict__ P1,
                                                  float* __restrict__ P2,
                                                  float2* __restrict__ nbuf) {
    __shared__ float w1s[384];
    __shared__ float b1s[64];
    const int tid = threadIdx.x;
    for (int u = tid; u < 384; u += 128) {
        const int r = u >> 6, c = u & 63;
        const int srow = (r < 3) ? r : (32 + r - 3);
        w1s[u] = W1[srow * 64 + c];
    }
    if (tid < 64) b1s[tid] = b1[tid];
    const int row = blockIdx.x * 128 + tid;
    const float x0 = x[row * 3 + 0], x1 = x[row * 3 + 1], x2 = x[row * 3 + 2];
    __syncthreads();
    float4* xp = (float4*)(xc + row * 32);
    xp[0] = make_float4(x0, x1, x2, 0.f);
    const float4 z4 = make_float4(0.f, 0.f, 0.f, 0.f);
#pragma unroll
    for (int u = 1; u < 8; ++u) xp[u] = z4;
    nbuf[row] = make_float2(x0 * x0 + x1 * x1 + x2 * x2, 0.f);
    float* p1p = P1 + row * 64;
    float* p2p = P2 + row * 64;
#pragma unroll
    for (int c = 0; c < 64; ++c) {
        p1p[c] = b1s[c] + x0 * w1s[c] + x1 * w1s[64 + c] + x2 * w1s[128 + c];
        p2p[c] = x0 * w1s[192 + c] + x1 * w1s[256 + c] + x2 * w1s[320 + c];
    }
}

// ---------------- edge pass 1: 512 threads, 16-col chunk per wave-pair ----
__global__ __launch_bounds__(512) void k_edge1(const float* __restrict__ xc,
                                               const float2* __restrict__ nbuf,
                                               const float* __restrict__ P1,
                                               const float* __restrict__ P2,
                                               const float* __restrict__ W1,
                                               float* __restrict__ stA) {
    __shared__ float xs[128 * 33];
    __shared__ float ddot[1024];        // holds DIST after dot phase
    __shared__ float2 nls[128];
    __shared__ float p1s[512];          // 8 il rows of P1
    __shared__ float red[256];          // 8 waves x 32 stats
    const int tid = threadIdx.x;
    const int b = blockIdx.x >> 4;
    const int ibase = (blockIdx.x & 15) * 8;
    const float* xg = xc + b * 4096;
    for (int u = tid; u < 4096; u += 512) xs[(u >> 5) * 33 + (u & 31)] = xg[u];
    if (tid < 128) nls[tid] = nbuf[b * 128 + tid];
    p1s[tid] = P1[(b * 128 + ibase + (tid >> 6)) * 64 + (tid & 63)];
    __syncthreads();
    {   // dot phase: 8 il rows x 128 j, 2 dists/thread (dist hoisted here)
        const int il = tid >> 6, jb = tid & 63;
        const float* xi = &xs[(ibase + il) * 33];
        const float nix = nls[ibase + il].x;
        float xi_r[31];
#pragma unroll
        for (int k = 0; k < 31; ++k) xi_r[k] = xi[k];
        for (int q = 0; q < 2; ++q) {
            const int j = jb + 64 * q;
            const float* xj = &xs[j * 33];
            float d = 0.f;
#pragma unroll
            for (int k = 0; k < 31; ++k) d = fmaf(xi_r[k], xj[k], d);
            ddot[il * 128 + j] = sqrtf(fmaxf(nix + nls[j].x - 2.f * d, 0.f));
        }
    }
    __syncthreads();
    const int w = tid >> 6, l = tid & 63;
    const int tq = tid & 127;           // j row
    const int ch = (tid >> 7) * 16;     // this wave-pair's 16-col chunk
    const float2 nj = nls[tq];
    float4 p2v[4], wav[4], wbv[4];
    {
        const float* p2r = P2 + (b * 128 + tq) * 64 + ch;
        const float* war = W1 + 64 * 64 + ch;
        const float* wbr = W1 + 65 * 64 + ch;
#pragma unroll
        for (int u = 0; u < 4; ++u) {
            p2v[u] = *(const float4*)(p2r + u * 4);
            wav[u] = *(const float4*)(war + u * 4);
            wbv[u] = *(const float4*)(wbr + u * 4);
        }
    }
    float sum[16], sq[16];
#pragma unroll
    for (int k = 0; k < 16; ++k) { sum[k] = 0.f; sq[k] = 0.f; }
#pragma unroll 1
    for (int c = 0; c < 8; ++c) {
        const float2 ni = nls[ibase + c];
        const float dist = ddot[c * 128 + tq];
        const float itf = 1.f - (nj.y - ni.y);
        const float* p1r = &p1s[c * 64 + ch];
#pragma unroll
        for (int u = 0; u < 4; ++u) {
            const float4 p1v = *(const float4*)(p1r + u * 4);
            const float4 p2q = p2v[u];
            const float4 wa = wav[u];
            const float4 wb = wbv[u];
            float y0 = fmaf(itf, wb.x, fmaf(dist, wa.x, p1v.x + p2q.x));
            float y1 = fmaf(itf, wb.y, fmaf(dist, wa.y, p1v.y + p2q.y));
            float y2 = fmaf(itf, wb.z, fmaf(dist, wa.z, p1v.z + p2q.z));
            float y3 = fmaf(itf, wb.w, fmaf(dist, wa.w, p1v.w + p2q.w));
            y0 = LRELU(y0); y1 = LRELU(y1); y2 = LRELU(y2); y3 = LRELU(y3);
            sum[4*u+0] += y0; sq[4*u+0] += y0 * y0;
            sum[4*u+1] += y1; sq[4*u+1] += y1 * y1;
            sum[4*u+2] += y2; sq[4*u+2] += y2 * y2;
            sum[4*u+3] += y3; sq[4*u+3] += y3 * y3;
        }
    }
    // reduce-scatter over THIS WAVE's 32 stats (sum[0..15]|sq[0..15]).
    // Stage order (bit -> index weight): b5->16, b4->8, b3->4, b2->2, b1->1;
    // final mask-1 plain add completes the 64-lane reduction. Lane l ends
    // holding stat idx = l>>1 (duplicated even/odd).
    {
        const int b5 = (l >> 5) & 1;
#pragma unroll
        for (int i = 0; i < 16; ++i) {
            const float keep = b5 ? sq[i] : sum[i];
            const float send = b5 ? sum[i] : sq[i];
            sum[i] = keep + __shfl_xor(send, 32, 64);
        }
        const int b4 = (l >> 4) & 1;
#pragma unroll
        for (int i = 0; i < 8; ++i) {
            const float keep = b4 ? sum[i + 8] : sum[i];
            const float send = b4 ? sum[i] : sum[i + 8];
            sum[i] = keep + __shfl_xor(send, 16, 64);
        }
        const int b3 = (l >> 3) & 1;
#pragma unroll
        for (int i = 0; i < 4; ++i) {
            const float keep = b3 ? sum[i + 4] : sum[i];
            const float send = b3 ? sum[i] : sum[i + 4];
            sum[i] = keep + __shfl_xor(send, 8, 64);
        }
        const int b2 = (l >> 2) & 1;
#pragma unroll
        for (int i = 0; i < 2; ++i) {
            const float keep = b2 ? sum[i + 2] : sum[i];
            const float send = b2 ? sum[i] : sum[i + 2];
            sum[i] = keep + __shfl_xor(send, 4, 64);
        }
        const int b1 = (l >> 1) & 1;
        {
            const float keep = b1 ? sum[1] : sum[0];
            const float send = b1 ? sum[0] : sum[1];
            sum[0] = keep + __shfl_xor(send, 2, 64);
        }
        sum[0] += __shfl_xor(sum[0], 1, 64);   // final plain add over lane bit 0
    }
    if ((l & 1) == 0) red[w * 32 + (l >> 1)] = sum[0];
    __syncthreads();
    // combine per wave-PAIR: pair p (waves 2p,2p+1) covers cols [16p,16p+16)
    if (tid < 128) {
        const int p = tid >> 5;          // 0..3
        const int s = tid & 31;          // stat index
        const float val = red[p * 64 + s] + red[p * 64 + 32 + s];
        const int col = p * 16 + (s & 15);
        const int idx = (s < 16) ? col : (64 + col);   // stA: [0..63]=sum, [64..127]=sq
        atomicAdd(stA + idx, val);
    }
}

// ---------------- edge pass 2: 512 threads, 1 M-tile/wave ----------------
__global__ __launch_bounds__(512) void k_edge2(const float* __restrict__ xc,
                                               const float2* __restrict__ nbuf,
                                               const float* __restrict__ P1,
                                               const float* __restrict__ P2,
                                               const float* __restrict__ W1,
                                               const float* __restrict__ W2,
                                               const float* __restrict__ b2g,
                                               const float* __restrict__ g1,
                                               const float* __restrict__ bt1,
                                               const float* __restrict__ stA,
                                               float* __restrict__ stB,
                                               float* __restrict__ aggp) {
    __shared__ __align__(16) char smem_u[16896];     // xs (dot) / cbAll (16KB) after
    __shared__ float ddot[1024];                     // holds DIST after dot phase
    __shared__ float2 nls[128];
    __shared__ unsigned short wfbs[4096];            // W2' frags: hi [0..2048), lo [2048..)
    __shared__ float s1s[64], t1s[64];
    __shared__ float p1s[512];                       // 8 il rows of P1
    __shared__ float part[256];
    __shared__ float b2ps[32];
    __shared__ float aggl[256];
    __shared__ float sqil[256];
    float* xs = (float*)smem_u;
    float* cbAll = (float*)smem_u;                   // [8 chunks][8 waves][64 slots]
    const int tid = threadIdx.x;
    const int b = blockIdx.x >> 4;
    const int ibase = (blockIdx.x & 15) * 8;
    const float* xg = xc + b * 4096;
    for (int u = tid; u < 4096; u += 512) xs[(u >> 5) * 33 + (u & 31)] = xg[u];
    if (tid < 128) nls[tid] = nbuf[b * 128 + tid];
    p1s[tid] = P1[(b * 128 + ibase + (tid >> 6)) * 64 + (tid & 63)];
    if (tid < 64) {
        const float ic = 1.f / 1048576.f;
        const float mu = stA[tid] * ic;
        const float var = stA[64 + tid] * ic - mu * mu;
        const float sv = g1[tid] * rsqrtf(var + BN_EPS);
        s1s[tid] = sv;
        t1s[tid] = bt1[tid] - mu * sv;
    }
    __syncthreads();
    {   // dot phase: 8 il rows x 128 j, 2 dists/thread (dist hoisted here)
        const int il = tid >> 6, jb = tid & 63;
        const float* xi = &xs[(ibase + il) * 33];
        const float nix = nls[ibase + il].x;
        float xi_r[31];
#pragma unroll
        for (int k = 0; k < 31; ++k) xi_r[k] = xi[k];
        for (int q = 0; q < 2; ++q) {
            const int j = jb + 64 * q;
            const float* xj = &xs[j * 33];
            float d = 0.f;
#pragma unroll
            for (int k = 0; k < 31; ++k) d = fmaf(xi_r[k], xj[k], d);
            ddot[il * 128 + j] = sqrtf(fmaxf(nix + nls[j].x - 2.f * d, 0.f));
        }
    }
    if (tid < 256) {   // W2' hi/lo fragments into LDS (B-fragment order)
        const int ks2n = tid >> 6, L = tid & 63;
        const int ks = ks2n >> 1, n = ks2n & 1;
#pragma unroll
        for (int e = 0; e < 8; ++e) {
            const int k = (L >> 4) * 8 + e + 32 * ks;
            const int col = n * 16 + (L & 15);
            const float wv = W2[k * 32 + col] * s1s[k];
            const unsigned short hi = bf16rne(wv);
            const unsigned short lo = bf16rne(wv - bf16tof(hi));
            wfbs[(ks2n * 64 + L) * 8 + e] = hi;
            wfbs[2048 + (ks2n * 64 + L) * 8 + e] = lo;
        }
    }
    if (tid < 256) {   // b2' partials
        const int colp = tid & 31, kg2 = tid >> 5;
        float p = 0.f;
#pragma unroll
        for (int e = 0; e < 8; ++e) {
            const int k = kg2 * 8 + e;
            p = fmaf(t1s[k], W2[k * 32 + colp], p);
        }
        part[kg2 * 32 + colp] = p;
    }
    __syncthreads();
    if (tid < 32) {
        float acc = b2g[tid];
#pragma unroll
        for (int g = 0; g < 8; ++g) acc += part[g * 32 + tid];
        b2ps[tid] = acc;
    }
    const int w = tid >> 6, l = tid & 63;
    short8v bfh[2][2], bfl[2][2];
#pragma unroll
    for (int ks = 0; ks < 2; ++ks)
#pragma unroll
        for (int n = 0; n < 2; ++n) {
            bfh[ks][n] = *(const short8v*)(wfbs + ((ks * 2 + n) * 64 + l) * 8);
            bfl[ks][n] = *(const short8v*)(wfbs + 2048 + ((ks * 2 + n) * 64 + l) * 8);
        }
    __syncthreads();                     // b2ps ready; xs dead -> cbAll reuse
    const float b2p0 = b2ps[l & 15];
    const float b2p1 = b2ps[16 + (l & 15)];
    const int kb = (l >> 4) * 8;         // this lane's k-slice base
    const int lb4 = (l >> 4) & 1;        // epilogue scatter bits
    const int lb5 = (l >> 5) & 1;
    const float* wab = W1 + 64 * 64;
    const float* wbb = W1 + 65 * 64;
    const float4 waA0 = *(const float4*)(wab + kb);
    const float4 waA1 = *(const float4*)(wab + kb + 4);
    const float4 waB0 = *(const float4*)(wab + 32 + kb);
    const float4 waB1 = *(const float4*)(wab + 32 + kb + 4);
    const float4 wbA0 = *(const float4*)(wbb + kb);
    const float4 wbA1 = *(const float4*)(wbb + kb + 4);
    const float4 wbB0 = *(const float4*)(wbb + 32 + kb);
    const float4 wbB1 = *(const float4*)(wbb + 32 + kb + 4);
    const int jrow = w * 16 + (l & 15);  // ONE M-tile per wave
    const float2 nj = nls[jrow];
    float4 p2rv[4];
    {
        const float* p2b = P2 + (b * 128 + jrow) * 64;
        p2rv[0] = *(const float4*)(p2b + kb);
        p2rv[1] = *(const float4*)(p2b + kb + 4);
        p2rv[2] = *(const float4*)(p2b + 32 + kb);
        p2rv[3] = *(const float4*)(p2b + 32 + kb + 4);
    }

#pragma unroll 1
    for (int c = 0; c < 8; ++c) {
        const float2 ni = nls[ibase + c];
        const float* p1b = &p1s[c * 64];
        const float4 p1A0 = *(const float4*)(p1b + kb);
        const float4 p1A1 = *(const float4*)(p1b + kb + 4);
        const float4 p1B0 = *(const float4*)(p1b + 32 + kb);
        const float4 p1B1 = *(const float4*)(p1b + 32 + kb + 4);
        const float dist = ddot[c * 128 + jrow];
        const float itf = 1.f - (nj.y - ni.y);
        const float4 p20 = p2rv[0];
        const float4 p21 = p2rv[1];
        const float4 p22 = p2rv[2];
        const float4 p23 = p2rv[3];
        float ya[8], yb[8];
        ya[0] = LRELU(fmaf(itf, wbA0.x, fmaf(dist, waA0.x, p1A0.x + p20.x)));
        ya[1] = LRELU(fmaf(itf, wbA0.y, fmaf(dist, waA0.y, p1A0.y + p20.y)));
        ya[2] = LRELU(fmaf(itf, wbA0.z, fmaf(dist, waA0.z, p1A0.z + p20.z)));
        ya[3] = LRELU(fmaf(itf, wbA0.w, fmaf(dist, waA0.w, p1A0.w + p20.w)));
        ya[4] = LRELU(fmaf(itf, wbA1.x, fmaf(dist, waA1.x, p1A1.x + p21.x)));
        ya[5] = LRELU(fmaf(itf, wbA1.y, fmaf(dist, waA1.y, p1A1.y + p21.y)));
        ya[6] = LRELU(fmaf(itf, wbA1.z, fmaf(dist, waA1.z, p1A1.z + p21.z)));
        ya[7] = LRELU(fmaf(itf, wbA1.w, fmaf(dist, waA1.w, p1A1.w + p21.w)));
        yb[0] = LRELU(fmaf(itf, wbB0.x, fmaf(dist, waB0.x, p1B0.x + p22.x)));
        yb[1] = LRELU(fmaf(itf, wbB0.y, fmaf(dist, waB0.y, p1B0.y + p22.y)));
        yb[2] = LRELU(fmaf(itf, wbB0.z, fmaf(dist, waB0.z, p1B0.z + p22.z)));
        yb[3] = LRELU(fmaf(itf, wbB0.w, fmaf(dist, waB0.w, p1B0.w + p22.w)));
        yb[4] = LRELU(fmaf(itf, wbB1.x, fmaf(dist, waB1.x, p1B1.x + p23.x)));
        yb[5] = LRELU(fmaf(itf, wbB1.y, fmaf(dist, waB1.y, p1B1.y + p23.y)));
        yb[6] = LRELU(fmaf(itf, wbB1.z, fmaf(dist, waB1.z, p1B1.z + p23.z)));
        yb[7] = LRELU(fmaf(itf, wbB1.w, fmaf(dist, waB1.w, p1B1.w + p23.w)));
        U8 a0h, a0l, a1h, a1l;
        cvt8(ya, a0h.u, a0l.u);
        cvt8(yb, a1h.u, a1l.u);
        f32x4 acc0 = {0.f, 0.f, 0.f, 0.f};
        f32x4 acc1 = {0.f, 0.f, 0.f, 0.f};
        acc0 = __builtin_amdgcn_mfma_f32_16x16x32_bf16(a0h.v, bfh[0][0], acc0, 0, 0, 0);
        acc0 = __builtin_amdgcn_mfma_f32_16x16x32_bf16(a0h.v, bfl[0][0], acc0, 0, 0, 0);
        acc0 = __builtin_amdgcn_mfma_f32_16x16x32_bf16(a0l.v, bfh[0][0], acc0, 0, 0, 0);
        acc0 = __builtin_amdgcn_mfma_f32_16x16x32_bf16(a1h.v, bfh[1][0], acc0, 0, 0, 0);
        acc0 = __builtin_amdgcn_mfma_f32_16x16x32_bf16(a1h.v, bfl[1][0], acc0, 0, 0, 0);
        acc0 = __builtin_amdgcn_mfma_f32_16x16x32_bf16(a1l.v, bfh[1][0], acc0, 0, 0, 0);
        acc1 = __builtin_amdgcn_mfma_f32_16x16x32_bf16(a0h.v, bfh[0][1], acc1, 0, 0, 0);
        acc1 = __builtin_amdgcn_mfma_f32_16x16x32_bf16(a0h.v, bfl[0][1], acc1, 0, 0, 0);
        acc1 = __builtin_amdgcn_mfma_f32_16x16x32_bf16(a0l.v, bfh[0][1], acc1, 0, 0, 0);
        acc1 = __builtin_amdgcn_mfma_f32_16x16x32_bf16(a1h.v, bfh[1][1], acc1, 0, 0, 0);
        acc1 = __builtin_amdgcn_mfma_f32_16x16x32_bf16(a1h.v, bfl[1][1], acc1, 0, 0, 0);
        acc1 = __builtin_amdgcn_mfma_f32_16x16x32_bf16(a1l.v, bfh[1][1], acc1, 0, 0, 0);
        float s0 = 0.f, q0 = 0.f, s1 = 0.f, q1 = 0.f;
#pragma unroll
        for (int r4 = 0; r4 < 4; ++r4) {
            const float z0 = LRELU(acc0[r4] + b2p0);
            const float z1 = LRELU(acc1[r4] + b2p1);
            s0 += z0; q0 += z0 * z0;
            s1 += z1; q1 += z1 * z1;
        }
        // reduce-scatter over lane bits 4,5: lane group keeps one of {s0,s1,q0,q1}
        float sA = lb4 ? s1 : s0;
        float sB = lb4 ? s0 : s1;
        float qA = lb4 ? q1 : q0;
        float qB = lb4 ? q0 : q1;
        sA += __shfl_xor(sB, 16, 64);
        qA += __shfl_xor(qB, 16, 64);
        float vA = lb5 ? qA : sA;
        float vB = lb5 ? sA : qA;
        vA += __shfl_xor(vB, 32, 64);
        // slot: [s c0-15 | s c16-31 | q c0-15 | q c16-31] per wave
        cbAll[c * 512 + w * 64 + lb5 * 32 + lb4 * 16 + (l & 15)] = vA;
    }
    __syncthreads();
    if (tid < 256) {
        const int c2 = tid >> 5, col = tid & 31;
        const float* base = cbAll + c2 * 512;
        float s = 0.f, qq = 0.f;
#pragma unroll
        for (int wv = 0; wv < 8; ++wv) {
            s  += base[wv * 64 + col];
            qq += base[wv * 64 + 32 + col];
        }
        aggp[(b * 128 + ibase + c2) * 32 + col] = s;
        aggl[c2 * 32 + col] = s;
        sqil[c2 * 32 + col] = qq;
    }
    __syncthreads();
    if (tid < 32) {
        float s = 0.f, qq = 0.f;
#pragma unroll
        for (int il3 = 0; il3 < 8; ++il3) { s += aggl[il3 * 32 + tid]; qq += sqil[il3 * 32 + tid]; }
        atomicAdd(stB + tid, s);
        atomicAdd(stB + 32 + tid, qq);
    }
}

// ---------------- software grid barrier (all blocks co-resident) ----------------
__device__ __forceinline__ void gbar(unsigned int* ctr, unsigned int target) {
    __syncthreads();
    if (threadIdx.x == 0) {
        __hip_atomic_fetch_add(ctr, 1u, __ATOMIC_ACQ_REL, __HIP_MEMORY_SCOPE_AGENT);
        while (__hip_atomic_load(ctr, __ATOMIC_ACQUIRE, __HIP_MEMORY_SCOPE_AGENT) < target) {
            __builtin_amdgcn_s_sleep(2);
        }
    }
    __syncthreads();
}

// ---------------- fused node MLP: 4 threads/row, 128 blocks x 256 threads ----
// row = blockIdx*64 + (tid>>2); part = tid&3 owns output cols [8p, 8p+8).
__global__ __launch_bounds__(256) void k_nodeF(
    const float* __restrict__ aggp, const float* __restrict__ xc,
    const float* __restrict__ W0, const float* __restrict__ b0,
    const float* __restrict__ stB, const float* __restrict__ g2, const float* __restrict__ bt2,
    const float* __restrict__ W1m, const float* __restrict__ b1m,
    float* __restrict__ stC, const float* __restrict__ gC, const float* __restrict__ btC,
    const float* __restrict__ W2m, const float* __restrict__ b2m,
    float* __restrict__ stD, const float* __restrict__ gD, const float* __restrict__ btD,
    float* __restrict__ xout,
    const float* __restrict__ W1n, const float* __restrict__ b1n,
    float* __restrict__ P1, float* __restrict__ P2, float2* __restrict__ nbuf,
    unsigned int* __restrict__ bar, int doPrep)
{
    __shared__ float w0s[2048];
    __shared__ float wms[1024];
    __shared__ float wus[1024];
    __shared__ float w1s[4096];
    __shared__ float b0s[32], s2s[32], t2s[32];
    __shared__ float bms[32], sCs[32], tCs[32];
    __shared__ float bus[32], sDs[32], tDs[32];
    __shared__ float b1s[64];
    __shared__ float red[256];
    const int tid = threadIdx.x;
    const int l = tid & 63, w = tid >> 6;
    const int part = tid & 3;
    const int row = blockIdx.x * 64 + (tid >> 2);
    const int ob = part * 8;            // this thread's output col base (8 cols)
    const int gbase = l & ~3;           // base lane of this row's 4-lane group
    for (int k = tid; k < 2048; k += 256) w0s[k] = W0[k];
    for (int k = tid; k < 1024; k += 256) { wms[k] = W1m[k]; wus[k] = W2m[k]; }
    if (doPrep) {
        for (int k = tid; k < 4096; k += 256) w1s[k] = W1n[k];
        if (tid < 64) b1s[tid] = b1n[tid];
    }
    if (tid < 32) {
        b0s[tid] = b0[tid]; bms[tid] = b1m[tid]; bus[tid] = b2m[tid];
        const float ic = 1.f / 1048576.f;
        const float mu = stB[tid] * ic;
        const float var = stB[32 + tid] * ic - mu * mu;
        const float sv = g2[tid] * rsqrtf(var + BN_EPS);
        s2s[tid] = sv; t2s[tid] = bt2[tid] - mu * sv;
    }
    __syncthreads();
    // ---- load full row input h[64] (4x duplicated across the row's lanes) ----
    float h[64];
    {
        const float4* ap = (const float4*)(aggp + row * 32);
        const float4* xp = (const float4*)(xc + row * 32);
#pragma unroll
        for (int u = 0; u < 8; ++u) {
            const float4 a = ap[u];
            h[4*u+0] = fmaf(s2s[4*u+0], a.x, 128.f * t2s[4*u+0]);
            h[4*u+1] = fmaf(s2s[4*u+1], a.y, 128.f * t2s[4*u+1]);
            h[4*u+2] = fmaf(s2s[4*u+2], a.z, 128.f * t2s[4*u+2]);
            h[4*u+3] = fmaf(s2s[4*u+3], a.w, 128.f * t2s[4*u+3]);
            const float4 xv = xp[u];
            h[32+4*u+0] = xv.x; h[32+4*u+1] = xv.y; h[32+4*u+2] = xv.z; h[32+4*u+3] = xv.w;
        }
    }
    // ---- GEMM1: 8 outputs ----
    float v[8];
#pragma unroll
    for (int oo = 0; oo < 8; oo += 4) {
        const int o0 = ob + oo;
        float z0 = b0s[o0], z1 = b0s[o0+1], z2 = b0s[o0+2], z3 = b0s[o0+3];
#pragma unroll
        for (int k = 0; k < 64; ++k) {
            const float4 wv = *(const float4*)&w0s[k * 32 + o0];
            const float hv = h[k];
            z0 = fmaf(hv, wv.x, z0); z1 = fmaf(hv, wv.y, z1);
            z2 = fmaf(hv, wv.z, z2); z3 = fmaf(hv, wv.w, z3);
        }
        v[oo] = LRELU(z0); v[oo+1] = LRELU(z1); v[oo+2] = LRELU(z2); v[oo+3] = LRELU(z3);
    }
    // ---- stats of v -> stC (butterfly over 16 rows of the wave) ----
    {
        float st[16];
#pragma unroll
        for (int i = 0; i < 8; ++i) { st[i] = v[i]; st[8 + i] = v[i] * v[i]; }
#pragma unroll
        for (int m = 4; m <= 32; m <<= 1) {
#pragma unroll
            for (int i = 0; i < 16; ++i) st[i] += __shfl_xor(st[i], m, 64);
        }
        if (l < 4) {
#pragma unroll
            for (int i = 0; i < 16; ++i) red[w * 64 + (l & 3) * 16 + i] = st[i];
        }
    }
    __syncthreads();
    if (tid < 64) {
        const float val = red[tid] + red[64 + tid] + red[128 + tid] + red[192 + tid];
        const int p2i = tid >> 4;
        const int ii = tid & 15;
        const int col = p2i * 8 + (ii & 7);
        const int isq = (ii >> 3) & 1;
        atomicAdd(stC + isq * 32 + col, val);
    }
    gbar(bar + 0, 128);
    if (tid < 32) {
        const float ic = 1.f / 8192.f;
        const float mu = __hip_atomic_load(stC + tid, __ATOMIC_RELAXED, __HIP_MEMORY_SCOPE_AGENT) * ic;
        const float sq = __hip_atomic_load(stC + 32 + tid, __ATOMIC_RELAXED, __HIP_MEMORY_SCOPE_AGENT) * ic;
        const float var = sq - mu * mu;
        const float sv = gC[tid] * rsqrtf(var + BN_EPS);
        sCs[tid] = sv; tCs[tid] = btC[tid] - mu * sv;
    }
    __syncthreads();
    // ---- all-gather v -> vf[32]; hh = BN ----
    float hh[32];
    {
#pragma unroll
        for (int g = 0; g < 4; ++g) {
#pragma unroll
            for (int i = 0; i < 8; ++i) {
                const float val = __shfl(v[i], gbase + g, 64);
                hh[g * 8 + i] = fmaf(sCs[g * 8 + i], val, tCs[g * 8 + i]);
            }
        }
    }
    // ---- GEMM2: 8 outputs ----
    float v2[8];
#pragma unroll
    for (int oo = 0; oo < 8; oo += 4) {
        const int o0 = ob + oo;
        float z0 = bms[o0], z1 = bms[o0+1], z2 = bms[o0+2], z3 = bms[o0+3];
#pragma unroll
        for (int k = 0; k < 32; ++k) {
            const float4 wv = *(const float4*)&wms[k * 32 + o0];
            const float hv = hh[k];
            z0 = fmaf(hv, wv.x, z0); z1 = fmaf(hv, wv.y, z1);
            z2 = fmaf(hv, wv.z, z2); z3 = fmaf(hv, wv.w, z3);
        }
        v2[oo] = LRELU(z0); v2[oo+1] = LRELU(z1); v2[oo+2] = LRELU(z2); v2[oo+3] = LRELU(z3);
    }
    // ---- stats of v2 -> stD ----
    {
        float st[16];
#pragma unroll
        for (int i = 0; i < 8; ++i) { st[i] = v2[i]; st[8 + i] = v2[i] * v2[i]; }
#pragma unroll
        for (int m = 4; m <= 32; m <<= 1) {
#pragma unroll
            for (int i = 0; i < 16; ++i) st[i] += __shfl_xor(st[i], m, 64);
        }
        __syncthreads();                 // red reuse
        if (l < 4) {
#pragma unroll
            for (int i = 0; i < 16; ++i) red[w * 64 + (l & 3) * 16 + i] = st[i];
        }
    }
    __syncthreads();
    if (tid < 64) {
        const float val = red[tid] + red[64 + tid] + red[128 + tid] + red[192 + tid];
        const int p2i = tid >> 4;
        const int ii = tid & 15;
        const int col = p2i * 8 + (ii & 7);
        const int isq = (ii >> 3) & 1;
        atomicAdd(stD + isq * 32 + col, val);
    }
    gbar(bar + 1, 128);
    if (tid < 32) {
        const float ic = 1.f / 8192.f;
        const float mu = __hip_atomic_load(stD + tid, __ATOMIC_RELAXED, __HIP_MEMORY_SCOPE_AGENT) * ic;
        const float sq = __hip_atomic_load(stD + 32 + tid, __ATOMIC_RELAXED, __HIP_MEMORY_SCOPE_AGENT) * ic;
        const float var = sq - mu * mu;
        const float sv = gD[tid] * rsqrtf(var + BN_EPS);
        sDs[tid] = sv; tDs[tid] = btD[tid] - mu * sv;
    }
    __syncthreads();
    // ---- all-gather v2 -> h3 = BN(v2) ----
    float h3[32];
    {
#pragma unroll
        for (int g = 0; g < 4; ++g) {
#pragma unroll
            for (int i = 0; i < 8; ++i) {
                const float val = __shfl(v2[i], gbase + g, 64);
                h3[g * 8 + i] = fmaf(sDs[g * 8 + i], val, tDs[g * 8 + i]);
            }
        }
    }
    // ---- GEMM3 (Wu) + tanh: 8 outputs ----
    float xn[8];
#pragma unroll
    for (int oo = 0; oo < 8; oo += 4) {
        const int o0 = ob + oo;
        float z0 = bus[o0], z1 = bus[o0+1], z2 = bus[o0+2], z3 = bus[o0+3];
#pragma unroll
        for (int k = 0; k < 32; ++k) {
            const float4 wv = *(const float4*)&wus[k * 32 + o0];
            const float hv = h3[k];
            z0 = fmaf(hv, wv.x, z0); z1 = fmaf(hv, wv.y, z1);
            z2 = fmaf(hv, wv.z, z2); z3 = fmaf(hv, wv.w, z3);
        }
        xn[oo]   = tanhf(z0);
        xn[oo+1] = tanhf(z1);
        xn[oo+2] = tanhf(z2);
        xn[oo+3] = tanhf(z3);
    }
    {
        float* xp = xout + row * 32 + ob;
        *(float4*)(xp)     = make_float4(xn[0], xn[1], xn[2], xn[3]);
        *(float4*)(xp + 4) = make_float4(xn[4], xn[5], xn[6], xn[7]);
    }
    if (!doPrep) return;
    // ---- all-gather xn -> xnf[32]; prep P1/P2 cols [16p, 16p+16) ----
    float xnf[32];
    {
#pragma unroll
        for (int g = 0; g < 4; ++g) {
#pragma unroll
            for (int i = 0; i < 8; ++i) {
                xnf[g * 8 + i] = __shfl(xn[i], gbase + g, 64);
            }
        }
    }
    if (part == 0) {
        float n = 0.f;
#pragma unroll
        for (int k = 0; k < 31; ++k) n = fmaf(xnf[k], xnf[k], n);
        nbuf[row] = make_float2(n, xnf[31]);
    }
    const int cb = part * 16;
    float* p1p = P1 + row * 64 + cb;
    float* p2p = P2 + row * 64 + cb;
#pragma unroll
    for (int c0 = 0; c0 < 16; c0 += 4) {
        const int col = cb + c0;
        float a0 = b1s[col], a1 = b1s[col+1], a2 = b1s[col+2], a3 = b1s[col+3];
        float q0 = 0.f, q1 = 0.f, q2 = 0.f, q3 = 0.f;
#pragma unroll
        for (int k = 0; k < 32; ++k) {
            const float xv = xnf[k];
            const float4 wa = *(const float4*)&w1s[k * 64 + col];
            const float4 wb = *(const float4*)&w1s[(32 + k) * 64 + col];
            a0 = fmaf(xv, wa.x, a0); a1 = fmaf(xv, wa.y, a1);
            a2 = fmaf(xv, wa.z, a2); a3 = fmaf(xv, wa.w, a3);
            q0 = fmaf(xv, wb.x, q0); q1 = fmaf(xv, wb.y, q1);
            q2 = fmaf(xv, wb.z, q2); q3 = fmaf(xv, wb.w, q3);
        }
        *(float4*)(p1p + c0) = make_float4(a0, a1, a2, a3);
        *(float4*)(p2p + c0) = make_float4(q0, q1, q2, q3);
    }
}

extern "C" void kernel_launch(void* const* d_in, const int* in_sizes, int n_in,
                              void* d_out, int out_size, void* d_ws, size_t ws_size,
                              hipStream_t stream) {
    const float* x    = (const float*)d_in[0];
    const float* Wah  = (const float*)d_in[1];
    const float* bah  = (const float*)d_in[2];
    const float* Wa   = (const float*)d_in[3];
    const float* ba   = (const float*)d_in[4];
    const float* g_eh = (const float*)d_in[5];
    const float* b_eh = (const float*)d_in[6];
    const float* g_e  = (const float*)d_in[7];
    const float* b_e  = (const float*)d_in[8];
    const float* Wn0  = (const float*)d_in[9];
    const float* bn0  = (const float*)d_in[10];
    const float* Wn   = (const float*)d_in[11];
    const float* bnn  = (const float*)d_in[12];
    const float* g_n  = (const float*)d_in[13];
    const float* b_n  = (const float*)d_in[14];
    const float* Wu   = (const float*)d_in[15];
    const float* bu   = (const float*)d_in[16];

    float* ws    = (float*)d_ws;
    float* xc    = ws;                 // 262144
    float* aggp  = ws + 262144;        // 262144
    float* P1    = ws + 786432;        // 524288
    float* P2    = ws + 1310720;       // 524288
    float2* nbuf = (float2*)(ws + 1835008);  // 16384 float2
    float* stats = ws + 1867776;       // 1280 (320/step)
    unsigned int* bar = (unsigned int*)(ws + 1869056);  // 16 counters
    float* out   = (float*)d_out;

    hipMemsetAsync(stats, 0, (1280 + 16) * sizeof(float), stream);
    k_pad_prep<<<64, 128, 0, stream>>>(x, Wah, bah, xc, P1, P2, nbuf);

    for (int s = 0; s < 4; ++s) {
        const float* W1 = Wah + s * 66 * 64;
        const float* W2 = Wa + s * 64 * 32;
        const float* b2 = ba + s * 32;
        float* stA = stats + s * 320;
        float* stB = stA + 128;
        float* stC = stA + 192;
        float* stD = stA + 256;

        k_edge1<<<1024, 512, 0, stream>>>(xc, nbuf, P1, P2, W1, stA);
        k_edge2<<<1024, 512, 0, stream>>>(xc, nbuf, P1, P2, W1, W2, b2,
                                          g_eh + s * 64, b_eh + s * 64, stA, stB, aggp);
        k_nodeF<<<128, 256, 0, stream>>>(aggp, xc, Wn0 + s * 2048, bn0 + s * 32,
                                        stB, g_e + s * 32, b_e + s * 32,
                                        Wn + s * 1024, bnn + s * 32,
                                        stC, g_n + s * 64, b_n + s * 64,
                                        Wu + s * 1024, bu + s * 32,
                                        stD, g_n + s * 64 + 32, b_n + s * 64 + 32,
                                        (s == 3) ? out : xc,
                                        (s < 3) ? (Wah + (s + 1) * 66 * 64) : Wah,
                                        (s < 3) ? (bah + (s + 1) * 64) : bah,
                                        P1, P2, nbuf, bar + s * 2, (s < 3) ? 1 : 0);
    }
}